// Round 2
// baseline (718.117 us; speedup 1.0000x reference)
//
#include <hip/hip_runtime.h>
#include <math.h>

// x_seq [32,128,2048] f32, W [2048,2048] f32 (out = x·W^T), b/ln_w/ln_b [2048].
// Output: spikes [32,128,2048] f32 (0/1). Binary output => any flipped
// threshold decision fails absmax. Strategy: full fp64 pre-spike pipeline so
// h matches float64 ground truth to ~1e-13 (no order sensitivity).
constexpr int T_ = 32, B_ = 128, D_ = 2048;
constexpr int M_ = T_ * B_;                 // 4096 rows
constexpr double LN_EPS = 1e-5;

constexpr int BM = 128, BN = 128, BK = 16;

constexpr size_t YD_BYTES = (size_t)M_ * D_ * sizeof(double);   // 64 MiB
constexpr size_t ST_BYTES = (size_t)M_ * 2 * sizeof(double);    // 64 KiB

// ---------------------------------------------------------------------------
// GEMM, f64 accumulate. MODE 0: write Y as f64 to Yd (main path).
//                       MODE 1: write Y as f32 to Yf (small-ws fallback).
// ---------------------------------------------------------------------------
template <int MODE>
__global__ __launch_bounds__(256, 2) void gemm_k(
    const float* __restrict__ X, const float* __restrict__ W,
    const float* __restrict__ bias, double* __restrict__ Yd,
    float* __restrict__ Yf)
{
    __shared__ float As[BK][BM + 4];   // k-major f32 tiles (stride 132 = 33
    __shared__ float Bs[BK][BN + 4];   // float4s -> 16B-aligned rows)

    // XCD swizzle: 512 blocks % 8 == 0 -> bijective transpose mapping
    const int wid = blockIdx.x;
    const int swz = (wid & 7) * 64 + (wid >> 3);
    const int bx  = swz >> 5;          // n-tile 0..15
    const int by  = swz & 31;          // m-tile 0..31
    const int m0 = by * BM, n0 = bx * BN;
    const int tid = threadIdx.x;

    const int lr = tid >> 2;           // staging row 0..63
    const int lc = (tid & 3) << 2;     // staging k-quad 0,4,8,12
    const float* xg = X + (size_t)(m0 + lr) * D_ + lc;
    const float* wg = W + (size_t)(n0 + lr) * D_ + lc;

    const int tx = tid & 15;           // 8x8 microtile as 2x2 float4 clusters
    const int ty = tid >> 4;           // at offsets {0,64}

    double acc[8][8];
#pragma unroll
    for (int i = 0; i < 8; ++i)
#pragma unroll
        for (int j = 0; j < 8; ++j) acc[i][j] = 0.0;

    for (int k0 = 0; k0 < D_; k0 += BK) {
        float4 a0 = *(const float4*)(xg + k0);
        float4 a1 = *(const float4*)(xg + (size_t)64 * D_ + k0);
        float4 b0 = *(const float4*)(wg + k0);
        float4 b1 = *(const float4*)(wg + (size_t)64 * D_ + k0);
        __syncthreads();               // prior iter done reading LDS
        As[lc + 0][lr] = a0.x; As[lc + 1][lr] = a0.y;
        As[lc + 2][lr] = a0.z; As[lc + 3][lr] = a0.w;
        As[lc + 0][64 + lr] = a1.x; As[lc + 1][64 + lr] = a1.y;
        As[lc + 2][64 + lr] = a1.z; As[lc + 3][64 + lr] = a1.w;
        Bs[lc + 0][lr] = b0.x; Bs[lc + 1][lr] = b0.y;
        Bs[lc + 2][lr] = b0.z; Bs[lc + 3][lr] = b0.w;
        Bs[lc + 0][64 + lr] = b1.x; Bs[lc + 1][64 + lr] = b1.y;
        Bs[lc + 2][64 + lr] = b1.z; Bs[lc + 3][64 + lr] = b1.w;
        __syncthreads();
#pragma unroll
        for (int k = 0; k < BK; ++k) {
            float af[8], bf[8];
            *(float4*)&af[0] = *(const float4*)&As[k][ty * 4];
            *(float4*)&af[4] = *(const float4*)&As[k][64 + ty * 4];
            *(float4*)&bf[0] = *(const float4*)&Bs[k][tx * 4];
            *(float4*)&bf[4] = *(const float4*)&Bs[k][64 + tx * 4];
            double ad[8], bd[8];
#pragma unroll
            for (int i = 0; i < 8; ++i) { ad[i] = (double)af[i]; bd[i] = (double)bf[i]; }
#pragma unroll
            for (int i = 0; i < 8; ++i)
#pragma unroll
                for (int j = 0; j < 8; ++j)
                    acc[i][j] = fma(ad[i], bd[j], acc[i][j]);
        }
    }

#pragma unroll
    for (int jh = 0; jh < 2; ++jh) {
        const int col = n0 + jh * 64 + tx * 4;
        const float4 bb4 = *(const float4*)&bias[col];
        const double bb[4] = {(double)bb4.x, (double)bb4.y,
                              (double)bb4.z, (double)bb4.w};
#pragma unroll
        for (int ih = 0; ih < 2; ++ih) {
#pragma unroll
            for (int i = 0; i < 4; ++i) {
                const int r = m0 + ih * 64 + ty * 4 + i;
                if (MODE == 0) {
                    double* yp = Yd + (size_t)r * D_ + col;
                    double2 o01, o23;
                    o01.x = acc[ih * 4 + i][jh * 4 + 0] + bb[0];
                    o01.y = acc[ih * 4 + i][jh * 4 + 1] + bb[1];
                    o23.x = acc[ih * 4 + i][jh * 4 + 2] + bb[2];
                    o23.y = acc[ih * 4 + i][jh * 4 + 3] + bb[3];
                    ((double2*)yp)[0] = o01;
                    ((double2*)yp)[1] = o23;
                } else {
                    float4 o;
                    o.x = (float)(acc[ih * 4 + i][jh * 4 + 0] + bb[0]);
                    o.y = (float)(acc[ih * 4 + i][jh * 4 + 1] + bb[1]);
                    o.z = (float)(acc[ih * 4 + i][jh * 4 + 2] + bb[2]);
                    o.w = (float)(acc[ih * 4 + i][jh * 4 + 3] + bb[3]);
                    *(float4*)&Yf[(size_t)r * D_ + col] = o;
                }
            }
        }
    }
}

// ---------------------------------------------------------------------------
// Per-row LayerNorm stats in f64: stats[row] = {mean, rstd}
// ---------------------------------------------------------------------------
template <bool SRC64>
__global__ __launch_bounds__(256) void ln_stats_k(
    const void* __restrict__ Ysrc, double* __restrict__ stats)
{
    __shared__ double red[8];
    const int row = blockIdx.x;
    const int tid = threadIdx.x;
    double a[8];
    if constexpr (SRC64) {
        const double2* y = (const double2*)((const double*)Ysrc + (size_t)row * D_);
        double2 u0 = y[tid], u1 = y[tid + 256], u2 = y[tid + 512], u3 = y[tid + 768];
        a[0] = u0.x; a[1] = u0.y; a[2] = u1.x; a[3] = u1.y;
        a[4] = u2.x; a[5] = u2.y; a[6] = u3.x; a[7] = u3.y;
    } else {
        const float4* y = (const float4*)((const float*)Ysrc + (size_t)row * D_);
        float4 u0 = y[tid], u1 = y[tid + 256];
        a[0] = u0.x; a[1] = u0.y; a[2] = u0.z; a[3] = u0.w;
        a[4] = u1.x; a[5] = u1.y; a[6] = u1.z; a[7] = u1.w;
    }

    double s = 0.0;
#pragma unroll
    for (int i = 0; i < 8; ++i) s += a[i];
#pragma unroll
    for (int off = 32; off > 0; off >>= 1) s += __shfl_xor(s, off);
    const int lane = tid & 63, wv = tid >> 6;
    if (lane == 0) red[wv] = s;
    __syncthreads();
    const double mean = (red[0] + red[1] + red[2] + red[3]) * (1.0 / D_);

    double d2 = 0.0;
#pragma unroll
    for (int i = 0; i < 8; ++i) { double d = a[i] - mean; d2 += d * d; }
#pragma unroll
    for (int off = 32; off > 0; off >>= 1) d2 += __shfl_xor(d2, off);
    if (lane == 0) red[4 + wv] = d2;
    __syncthreads();
    if (tid == 0) {
        const double var = (red[4] + red[5] + red[6] + red[7]) * (1.0 / D_);
        stats[2 * row]     = mean;
        stats[2 * row + 1] = 1.0 / sqrt(var + LN_EPS);
    }
}

// ---------------------------------------------------------------------------
// LN-affine + residual + 32-step LIF in f64; spikes (f32) to d_out.
// h = v + (x - v)*0.5 (exact == /2.0); fire = (h - 1) >= 0; hard reset.
// ---------------------------------------------------------------------------
template <bool SRC64>
__global__ __launch_bounds__(256) void lif_k(
    const float* __restrict__ X, const float* __restrict__ lnw,
    const float* __restrict__ lnb, const double* __restrict__ stats,
    const void* __restrict__ Ysrc, float* __restrict__ out)
{
    const int q  = blockIdx.x * blockDim.x + threadIdx.x;  // 0..65535
    const int e4 = q & (D_ / 4 - 1);
    const int bi = q >> 9;

    const float4 w4 = ((const float4*)lnw)[e4];
    const float4 b4 = ((const float4*)lnb)[e4];
    const double w[4]  = {(double)w4.x, (double)w4.y, (double)w4.z, (double)w4.w};
    const double bb[4] = {(double)b4.x, (double)b4.y, (double)b4.z, (double)b4.w};
    double v[4] = {0.0, 0.0, 0.0, 0.0};

    for (int t = 0; t < T_; ++t) {
        const int row = t * B_ + bi;
        const double mu = stats[2 * row];
        const double rs = stats[2 * row + 1];
        double y[4];
        if constexpr (SRC64) {
            const double2* yp = (const double2*)((const double*)Ysrc +
                                                 (size_t)row * D_ + e4 * 4);
            double2 u0 = yp[0], u1 = yp[1];
            y[0] = u0.x; y[1] = u0.y; y[2] = u1.x; y[3] = u1.y;
        } else {
            float4 y4 = ((const float4*)Ysrc)[(size_t)row * (D_ / 4) + e4];
            y[0] = y4.x; y[1] = y4.y; y[2] = y4.z; y[3] = y4.w;
        }
        const float4 x4 = ((const float4*)X)[(size_t)row * (D_ / 4) + e4];
        const double xr[4] = {(double)x4.x, (double)x4.y, (double)x4.z, (double)x4.w};
        float sp[4];
#pragma unroll
        for (int c = 0; c < 4; ++c) {
            const double z   = (y[c] - mu) * rs * w[c] + bb[c];
            const double xin = z + xr[c];
            const double h   = v[c] + (xin - v[c]) * 0.5;
            const bool fire  = (h - 1.0) >= 0.0;
            sp[c] = fire ? 1.0f : 0.0f;
            v[c]  = fire ? 0.0 : h;
        }
        float4 o = {sp[0], sp[1], sp[2], sp[3]};
        ((float4*)out)[(size_t)row * (D_ / 4) + e4] = o;
    }
}

// ---------------------------------------------------------------------------
extern "C" void kernel_launch(void* const* d_in, const int* in_sizes, int n_in,
                              void* d_out, int out_size, void* d_ws, size_t ws_size,
                              hipStream_t stream)
{
    const float* X    = (const float*)d_in[0];
    const float* W    = (const float*)d_in[1];
    const float* bias = (const float*)d_in[2];
    const float* lnw  = (const float*)d_in[3];
    const float* lnb  = (const float*)d_in[4];
    float* out = (float*)d_out;

    const bool big = ws_size >= YD_BYTES + ST_BYTES;   // deterministic branch

    if (big) {
        double* Yd    = (double*)d_ws;
        double* stats = (double*)((char*)d_ws + YD_BYTES);
        gemm_k<0><<<dim3(512), dim3(256), 0, stream>>>(X, W, bias, Yd, nullptr);
        ln_stats_k<true><<<dim3(M_), dim3(256), 0, stream>>>(Yd, stats);
        lif_k<true><<<dim3((B_ * D_ / 4) / 256), dim3(256), 0, stream>>>(
            X, lnw, lnb, stats, Yd, out);
    } else {
        // fallback: Y as f32 in d_out (read then overwritten in place by lif)
        double* stats = (double*)d_ws;                 // needs 64 KiB
        gemm_k<1><<<dim3(512), dim3(256), 0, stream>>>(X, W, bias, nullptr, out);
        ln_stats_k<false><<<dim3(M_), dim3(256), 0, stream>>>(out, stats);
        lif_k<false><<<dim3((B_ * D_ / 4) / 256), dim3(256), 0, stream>>>(
            X, lnw, lnb, stats, out, out);
    }
}

// Round 4
// 558.003 us; speedup vs baseline: 1.2869x; 1.2869x over previous
//
#include <hip/hip_runtime.h>
#include <math.h>

// x_seq [32,128,2048] f32, W [2048,2048] f32 (out = x·W^T), b/ln_w/ln_b [2048].
// Output: spikes [32,128,2048] f32. f64 np reference + binary output => full
// fp64 pre-spike pipeline (round 2 passed, absmax 0.0, 718us VALU GEMM).
// Round 4: f64 MFMA GEMM with RUNTIME-PROBED C/D layout. Round 3 failed with
// hard-coded fragment layout; two probe mfmas (a=row-enc,b=1 / a=1,b=col-enc)
// discover the (lane,reg)->(row,col) relabel so the epilogue is correct for
// ANY layout with consistent lane->k grouping between A and B.
constexpr int T_ = 32, B_ = 128, D_ = 2048;
constexpr int M_ = T_ * B_;                 // 4096 rows
constexpr double LN_EPS = 1e-5;

constexpr size_t YD_BYTES = (size_t)M_ * D_ * sizeof(double);   // 64 MiB
constexpr size_t ST_BYTES = (size_t)M_ * 2 * sizeof(double);    // 64 KiB

#if defined(__has_builtin)
#if __has_builtin(__builtin_amdgcn_mfma_f64_16x16x4f64)
#define HAVE_MFMA_F64 1
#endif
#endif
#ifndef HAVE_MFMA_F64
#define HAVE_MFMA_F64 0
#endif

// ---------------------------------------------------------------------------
// GEMM Y = X*W^T + bias, f64.  MODE 0: Y as f64 to Yd.  MODE 1: f32 to Yf.
// ---------------------------------------------------------------------------
#if HAVE_MFMA_F64
typedef double d4 __attribute__((ext_vector_type(4)));
constexpr int BM = 128, BN = 128, BK = 32;

template <int MODE>
__global__ __launch_bounds__(256, 2) void gemm_k(
    const float* __restrict__ X, const float* __restrict__ W,
    const float* __restrict__ bias, double* __restrict__ Yd,
    float* __restrict__ Yf)
{
    __shared__ float As[BK][BM + 4];   // k-major f32 tiles
    __shared__ float Bs[BK][BN + 4];

    // XCD swizzle (512 blocks % 8 == 0 -> bijective)
    const int wid = blockIdx.x;
    const int swz = (wid & 7) * 64 + (wid >> 3);
    const int bx  = swz >> 5;          // n-tile 0..15
    const int by  = swz & 31;          // m-tile 0..31
    const int m0 = by * BM, n0 = bx * BN;
    const int tid = threadIdx.x;

    // staging: thread -> (row sr, 16-wide k-chunk sc)
    const int sr = tid >> 1;           // 0..127
    const int sc = (tid & 1) << 4;     // 0 or 16
    const float* xg = X + (size_t)(m0 + sr) * D_ + sc;
    const float* wg = W + (size_t)(n0 + sr) * D_ + sc;

    // wave -> 64x64 quadrant; lane -> assumed mfma fragment coords
    const int lane = tid & 63;
    const int wv   = tid >> 6;         // 0..3
    const int wr   = (wv >> 1) * 64;   // quadrant row offset
    const int wc   = (wv & 1) * 64;    // quadrant col offset
    const int li   = lane & 15;        // assumed i (A) / j (B)
    const int lk   = lane >> 4;        // assumed k

    // --- layout probes -----------------------------------------------------
    // P1[i][j] = sum_k A[i][k] with A-lane-value = assumed-row  -> 4*rho(i)
    // P2[i][j] = sum_k B[k][j] with B-lane-value = assumed-col  -> 4*sigma(j)
    // Valid for any A/B maps sharing the lane->k grouping (all known MFMA HW);
    // makes the epilogue independent of the true C/D register layout.
    d4 p1 = __builtin_amdgcn_mfma_f64_16x16x4f64((double)li, 1.0, (d4)0.0, 0, 0, 0);
    d4 p2 = __builtin_amdgcn_mfma_f64_16x16x4f64(1.0, (double)li, (d4)0.0, 0, 0, 0);
    int ri[4], cj[4];
#pragma unroll
    for (int v = 0; v < 4; ++v) {
        ri[v] = (int)(p1[v] * 0.25 + 0.5);   // assumed-row of acc slot v
        cj[v] = (int)(p2[v] * 0.25 + 0.5);   // assumed-col of acc slot v
    }

    d4 acc[4][4];
#pragma unroll
    for (int mt = 0; mt < 4; ++mt)
#pragma unroll
        for (int nt = 0; nt < 4; ++nt) acc[mt][nt] = (d4)0.0;

    for (int k0 = 0; k0 < D_; k0 += BK) {
        float4 xa[4], wb[4];
#pragma unroll
        for (int j = 0; j < 4; ++j) {
            xa[j] = *(const float4*)(xg + k0 + 4 * j);
            wb[j] = *(const float4*)(wg + k0 + 4 * j);
        }
        __syncthreads();               // prior iter done reading LDS
#pragma unroll
        for (int j = 0; j < 4; ++j)
#pragma unroll
            for (int e = 0; e < 4; ++e) {
                As[sc + 4 * j + e][sr] = ((const float*)&xa[j])[e];
                Bs[sc + 4 * j + e][sr] = ((const float*)&wb[j])[e];
            }
        __syncthreads();
#pragma unroll
        for (int s = 0; s < BK / 4; ++s) {
            const int k = 4 * s + lk;
            double a[4], b[4];
#pragma unroll
            for (int mt = 0; mt < 4; ++mt)
                a[mt] = (double)As[k][wr + mt * 16 + li];
#pragma unroll
            for (int nt = 0; nt < 4; ++nt)
                b[nt] = (double)Bs[k][wc + nt * 16 + li];
#pragma unroll
            for (int mt = 0; mt < 4; ++mt)
#pragma unroll
                for (int nt = 0; nt < 4; ++nt)
                    acc[mt][nt] = __builtin_amdgcn_mfma_f64_16x16x4f64(
                        a[mt], b[nt], acc[mt][nt], 0, 0, 0);
        }
    }

    // epilogue: scatter via probed relabel (layout-proof)
#pragma unroll
    for (int nt = 0; nt < 4; ++nt) {
#pragma unroll
        for (int mt = 0; mt < 4; ++mt) {
#pragma unroll
            for (int v = 0; v < 4; ++v) {
                const int row = m0 + wr + mt * 16 + ri[v];
                const int col = n0 + wc + nt * 16 + cj[v];
                const double val = acc[mt][nt][v] + (double)bias[col];
                if (MODE == 0) Yd[(size_t)row * D_ + col] = val;
                else           Yf[(size_t)row * D_ + col] = (float)val;
            }
        }
    }
}

#else  // !HAVE_MFMA_F64 — round-2 proven VALU fallback
constexpr int BM = 128, BN = 128, BK = 16;

template <int MODE>
__global__ __launch_bounds__(256, 2) void gemm_k(
    const float* __restrict__ X, const float* __restrict__ W,
    const float* __restrict__ bias, double* __restrict__ Yd,
    float* __restrict__ Yf)
{
    __shared__ float As[BK][BM + 4];
    __shared__ float Bs[BK][BN + 4];
    const int wid = blockIdx.x;
    const int swz = (wid & 7) * 64 + (wid >> 3);
    const int bx  = swz >> 5;
    const int by  = swz & 31;
    const int m0 = by * BM, n0 = bx * BN;
    const int tid = threadIdx.x;
    const int lr = tid >> 2;
    const int lc = (tid & 3) << 2;
    const float* xg = X + (size_t)(m0 + lr) * D_ + lc;
    const float* wg = W + (size_t)(n0 + lr) * D_ + lc;
    const int tx = tid & 15;
    const int ty = tid >> 4;

    double acc[8][8];
#pragma unroll
    for (int i = 0; i < 8; ++i)
#pragma unroll
        for (int j = 0; j < 8; ++j) acc[i][j] = 0.0;

    for (int k0 = 0; k0 < D_; k0 += BK) {
        float4 a0 = *(const float4*)(xg + k0);
        float4 a1 = *(const float4*)(xg + (size_t)64 * D_ + k0);
        float4 b0 = *(const float4*)(wg + k0);
        float4 b1 = *(const float4*)(wg + (size_t)64 * D_ + k0);
        __syncthreads();
        As[lc + 0][lr] = a0.x; As[lc + 1][lr] = a0.y;
        As[lc + 2][lr] = a0.z; As[lc + 3][lr] = a0.w;
        As[lc + 0][64 + lr] = a1.x; As[lc + 1][64 + lr] = a1.y;
        As[lc + 2][64 + lr] = a1.z; As[lc + 3][64 + lr] = a1.w;
        Bs[lc + 0][lr] = b0.x; Bs[lc + 1][lr] = b0.y;
        Bs[lc + 2][lr] = b0.z; Bs[lc + 3][lr] = b0.w;
        Bs[lc + 0][64 + lr] = b1.x; Bs[lc + 1][64 + lr] = b1.y;
        Bs[lc + 2][64 + lr] = b1.z; Bs[lc + 3][64 + lr] = b1.w;
        __syncthreads();
#pragma unroll
        for (int k = 0; k < BK; ++k) {
            float af[8], bf[8];
            *(float4*)&af[0] = *(const float4*)&As[k][ty * 4];
            *(float4*)&af[4] = *(const float4*)&As[k][64 + ty * 4];
            *(float4*)&bf[0] = *(const float4*)&Bs[k][tx * 4];
            *(float4*)&bf[4] = *(const float4*)&Bs[k][64 + tx * 4];
            double ad[8], bd[8];
#pragma unroll
            for (int i = 0; i < 8; ++i) { ad[i] = (double)af[i]; bd[i] = (double)bf[i]; }
#pragma unroll
            for (int i = 0; i < 8; ++i)
#pragma unroll
                for (int j = 0; j < 8; ++j)
                    acc[i][j] = fma(ad[i], bd[j], acc[i][j]);
        }
    }
#pragma unroll
    for (int jh = 0; jh < 2; ++jh) {
        const int col = n0 + jh * 64 + tx * 4;
        const float4 bb4 = *(const float4*)&bias[col];
        const double bb[4] = {(double)bb4.x, (double)bb4.y,
                              (double)bb4.z, (double)bb4.w};
#pragma unroll
        for (int ih = 0; ih < 2; ++ih)
#pragma unroll
            for (int i = 0; i < 4; ++i) {
                const int r = m0 + ih * 64 + ty * 4 + i;
#pragma unroll
                for (int v = 0; v < 4; ++v) {
                    const double val = acc[ih * 4 + i][jh * 4 + v] + bb[v];
                    if (MODE == 0) Yd[(size_t)r * D_ + col + v] = val;
                    else           Yf[(size_t)r * D_ + col + v] = (float)val;
                }
            }
    }
}
#endif  // HAVE_MFMA_F64

// ---------------------------------------------------------------------------
// Per-row LayerNorm stats in f64: stats[row] = {mean, rstd}
// ---------------------------------------------------------------------------
template <bool SRC64>
__global__ __launch_bounds__(256) void ln_stats_k(
    const void* __restrict__ Ysrc, double* __restrict__ stats)
{
    __shared__ double red[8];
    const int row = blockIdx.x;
    const int tid = threadIdx.x;
    double a[8];
    if constexpr (SRC64) {
        const double2* y = (const double2*)((const double*)Ysrc + (size_t)row * D_);
        double2 u0 = y[tid], u1 = y[tid + 256], u2 = y[tid + 512], u3 = y[tid + 768];
        a[0] = u0.x; a[1] = u0.y; a[2] = u1.x; a[3] = u1.y;
        a[4] = u2.x; a[5] = u2.y; a[6] = u3.x; a[7] = u3.y;
    } else {
        const float4* y = (const float4*)((const float*)Ysrc + (size_t)row * D_);
        float4 u0 = y[tid], u1 = y[tid + 256];
        a[0] = u0.x; a[1] = u0.y; a[2] = u0.z; a[3] = u0.w;
        a[4] = u1.x; a[5] = u1.y; a[6] = u1.z; a[7] = u1.w;
    }

    double s = 0.0;
#pragma unroll
    for (int i = 0; i < 8; ++i) s += a[i];
#pragma unroll
    for (int off = 32; off > 0; off >>= 1) s += __shfl_xor(s, off);
    const int lane = tid & 63, wv = tid >> 6;
    if (lane == 0) red[wv] = s;
    __syncthreads();
    const double mean = (red[0] + red[1] + red[2] + red[3]) * (1.0 / D_);

    double d2 = 0.0;
#pragma unroll
    for (int i = 0; i < 8; ++i) { double d = a[i] - mean; d2 += d * d; }
#pragma unroll
    for (int off = 32; off > 0; off >>= 1) d2 += __shfl_xor(d2, off);
    if (lane == 0) red[4 + wv] = d2;
    __syncthreads();
    if (tid == 0) {
        const double var = (red[4] + red[5] + red[6] + red[7]) * (1.0 / D_);
        stats[2 * row]     = mean;
        stats[2 * row + 1] = 1.0 / sqrt(var + LN_EPS);
    }
}

// ---------------------------------------------------------------------------
// LN-affine + residual + 32-step LIF in f64; spikes (f32) to d_out.
// ---------------------------------------------------------------------------
template <bool SRC64>
__global__ __launch_bounds__(256) void lif_k(
    const float* __restrict__ X, const float* __restrict__ lnw,
    const float* __restrict__ lnb, const double* __restrict__ stats,
    const void* __restrict__ Ysrc, float* __restrict__ out)
{
    const int q  = blockIdx.x * blockDim.x + threadIdx.x;  // 0..65535
    const int e4 = q & (D_ / 4 - 1);
    const int bi = q >> 9;

    const float4 w4 = ((const float4*)lnw)[e4];
    const float4 b4 = ((const float4*)lnb)[e4];
    const double w[4]  = {(double)w4.x, (double)w4.y, (double)w4.z, (double)w4.w};
    const double bb[4] = {(double)b4.x, (double)b4.y, (double)b4.z, (double)b4.w};
    double v[4] = {0.0, 0.0, 0.0, 0.0};

    for (int t = 0; t < T_; ++t) {
        const int row = t * B_ + bi;
        const double mu = stats[2 * row];
        const double rs = stats[2 * row + 1];
        double y[4];
        if constexpr (SRC64) {
            const double2* yp = (const double2*)((const double*)Ysrc +
                                                 (size_t)row * D_ + e4 * 4);
            double2 u0 = yp[0], u1 = yp[1];
            y[0] = u0.x; y[1] = u0.y; y[2] = u1.x; y[3] = u1.y;
        } else {
            float4 y4 = ((const float4*)Ysrc)[(size_t)row * (D_ / 4) + e4];
            y[0] = y4.x; y[1] = y4.y; y[2] = y4.z; y[3] = y4.w;
        }
        const float4 x4 = ((const float4*)X)[(size_t)row * (D_ / 4) + e4];
        const double xr[4] = {(double)x4.x, (double)x4.y, (double)x4.z, (double)x4.w};
        float sp[4];
#pragma unroll
        for (int c = 0; c < 4; ++c) {
            const double z   = (y[c] - mu) * rs * w[c] + bb[c];
            const double xin = z + xr[c];
            const double h   = v[c] + (xin - v[c]) * 0.5;
            const bool fire  = (h - 1.0) >= 0.0;
            sp[c] = fire ? 1.0f : 0.0f;
            v[c]  = fire ? 0.0 : h;
        }
        float4 o = {sp[0], sp[1], sp[2], sp[3]};
        ((float4*)out)[(size_t)row * (D_ / 4) + e4] = o;
    }
}

// ---------------------------------------------------------------------------
extern "C" void kernel_launch(void* const* d_in, const int* in_sizes, int n_in,
                              void* d_out, int out_size, void* d_ws, size_t ws_size,
                              hipStream_t stream)
{
    const float* X    = (const float*)d_in[0];
    const float* W    = (const float*)d_in[1];
    const float* bias = (const float*)d_in[2];
    const float* lnw  = (const float*)d_in[3];
    const float* lnb  = (const float*)d_in[4];
    float* out = (float*)d_out;

    const bool big = ws_size >= YD_BYTES + ST_BYTES;   // deterministic branch

    if (big) {
        double* Yd    = (double*)d_ws;
        double* stats = (double*)((char*)d_ws + YD_BYTES);
        gemm_k<0><<<dim3(512), dim3(256), 0, stream>>>(X, W, bias, Yd, nullptr);
        ln_stats_k<true><<<dim3(M_), dim3(256), 0, stream>>>(Yd, stats);
        lif_k<true><<<dim3((B_ * D_ / 4) / 256), dim3(256), 0, stream>>>(
            X, lnw, lnb, stats, Yd, out);
    } else {
        double* stats = (double*)d_ws;                 // needs 64 KiB
        gemm_k<1><<<dim3(512), dim3(256), 0, stream>>>(X, W, bias, nullptr, out);
        ln_stats_k<false><<<dim3(M_), dim3(256), 0, stream>>>(out, stats);
        lif_k<false><<<dim3((B_ * D_ / 4) / 256), dim3(256), 0, stream>>>(
            X, lnw, lnb, stats, out, out);
    }
}

// Round 5
// 549.237 us; speedup vs baseline: 1.3075x; 1.0160x over previous
//
#include <hip/hip_runtime.h>
#include <math.h>

// x_seq [32,128,2048] f32, W [2048,2048] f32 (out = x·W^T), b/ln_w/ln_b [2048].
// Output: spikes [32,128,2048] f32. f64 np reference + binary output => full
// fp64 pre-spike pipeline. Round 4 passed (558us, MfmaUtil 80.7%, probe-based
// C/D layout). Round 5: close the remaining ~19% matrix-pipe idle:
//  (a) double-buffered LDS + early global-load issue -> load latency and
//      vmcnt drain hide under the MFMA phase; one barrier per K-iter.
//  (b) LDS row stride 132->144 floats (stride%32==16): the four lk lane
//      groups land on bank offsets {0,16,0,16} -> exact 2 lanes/bank (free,
//      m136) instead of 4-way collisions at offsets {0,4,8,12}.
constexpr int T_ = 32, B_ = 128, D_ = 2048;
constexpr int M_ = T_ * B_;                 // 4096 rows
constexpr double LN_EPS = 1e-5;

constexpr size_t YD_BYTES = (size_t)M_ * D_ * sizeof(double);   // 64 MiB
constexpr size_t ST_BYTES = (size_t)M_ * 2 * sizeof(double);    // 64 KiB

#if defined(__has_builtin)
#if __has_builtin(__builtin_amdgcn_mfma_f64_16x16x4f64)
#define HAVE_MFMA_F64 1
#endif
#endif
#ifndef HAVE_MFMA_F64
#define HAVE_MFMA_F64 0
#endif

// ---------------------------------------------------------------------------
// GEMM Y = X*W^T + bias, f64.  MODE 0: Y as f64 to Yd.  MODE 1: f32 to Yf.
// ---------------------------------------------------------------------------
#if HAVE_MFMA_F64
typedef double d4 __attribute__((ext_vector_type(4)));
constexpr int BM = 128, BN = 128, BK = 32;
constexpr int LDP = BM + 16;               // row stride 144: 144%32==16

template <int MODE>
__global__ __launch_bounds__(256, 2) void gemm_k(
    const float* __restrict__ X, const float* __restrict__ W,
    const float* __restrict__ bias, double* __restrict__ Yd,
    float* __restrict__ Yf)
{
    __shared__ float As[2][BK][LDP];       // 2 x 18KB
    __shared__ float Bs[2][BK][LDP];       // total 73.7KB -> 2 blocks/CU

    // XCD swizzle (512 blocks % 8 == 0 -> bijective)
    const int wid = blockIdx.x;
    const int swz = (wid & 7) * 64 + (wid >> 3);
    const int bx  = swz >> 5;              // n-tile 0..15
    const int by  = swz & 31;              // m-tile 0..31
    const int m0 = by * BM, n0 = bx * BN;
    const int tid = threadIdx.x;

    // staging: thread -> (row sr, 16-wide k-chunk sc)
    const int sr = tid >> 1;               // 0..127
    const int sc = (tid & 1) << 4;         // 0 or 16
    const float* xg = X + (size_t)(m0 + sr) * D_ + sc;
    const float* wg = W + (size_t)(n0 + sr) * D_ + sc;

    // wave -> 64x64 quadrant; lane -> assumed mfma fragment coords
    const int lane = tid & 63;
    const int wv   = tid >> 6;
    const int wr   = (wv >> 1) * 64;
    const int wc   = (wv & 1) * 64;
    const int li   = lane & 15;            // assumed i (A) / j (B)
    const int lk   = lane >> 4;            // assumed k

    // layout probes: epilogue correct for ANY C/D register layout whose A/B
    // maps share the lane->k grouping (round-4 verified, absmax 0.0)
    d4 p1 = __builtin_amdgcn_mfma_f64_16x16x4f64((double)li, 1.0, (d4)0.0, 0, 0, 0);
    d4 p2 = __builtin_amdgcn_mfma_f64_16x16x4f64(1.0, (double)li, (d4)0.0, 0, 0, 0);
    int ri[4], cj[4];
#pragma unroll
    for (int v = 0; v < 4; ++v) {
        ri[v] = (int)(p1[v] * 0.25 + 0.5);
        cj[v] = (int)(p2[v] * 0.25 + 0.5);
    }

    d4 acc[4][4];
#pragma unroll
    for (int mt = 0; mt < 4; ++mt)
#pragma unroll
        for (int nt = 0; nt < 4; ++nt) acc[mt][nt] = (d4)0.0;

    float4 xa[4], wb[4];

    // ---- prologue: tile 0 -> regs -> LDS[0] ----
#pragma unroll
    for (int j = 0; j < 4; ++j) {
        xa[j] = *(const float4*)(xg + 4 * j);
        wb[j] = *(const float4*)(wg + 4 * j);
    }
#pragma unroll
    for (int j = 0; j < 4; ++j)
#pragma unroll
        for (int e = 0; e < 4; ++e) {
            As[0][sc + 4 * j + e][sr] = ((const float*)&xa[j])[e];
            Bs[0][sc + 4 * j + e][sr] = ((const float*)&wb[j])[e];
        }
    __syncthreads();

    int cur = 0;
    for (int k0 = 0; k0 < D_; k0 += BK) {
        const bool has_next = (k0 + BK < D_);
        if (has_next) {                    // issue next tile loads EARLY
#pragma unroll
            for (int j = 0; j < 4; ++j) {
                xa[j] = *(const float4*)(xg + k0 + BK + 4 * j);
                wb[j] = *(const float4*)(wg + k0 + BK + 4 * j);
            }
        }
        // ---- compute tile from LDS[cur]; load latency hides under this ----
#pragma unroll
        for (int s = 0; s < BK / 4; ++s) {
            const int k = 4 * s + lk;
            double a[4], b[4];
#pragma unroll
            for (int mt = 0; mt < 4; ++mt)
                a[mt] = (double)As[cur][k][wr + mt * 16 + li];
#pragma unroll
            for (int nt = 0; nt < 4; ++nt)
                b[nt] = (double)Bs[cur][k][wc + nt * 16 + li];
#pragma unroll
            for (int mt = 0; mt < 4; ++mt)
#pragma unroll
                for (int nt = 0; nt < 4; ++nt)
                    acc[mt][nt] = __builtin_amdgcn_mfma_f64_16x16x4f64(
                        a[mt], b[nt], acc[mt][nt], 0, 0, 0);
        }
        if (has_next) {                    // stage into other buffer, 1 barrier
            const int nxt = cur ^ 1;
#pragma unroll
            for (int j = 0; j < 4; ++j)
#pragma unroll
                for (int e = 0; e < 4; ++e) {
                    As[nxt][sc + 4 * j + e][sr] = ((const float*)&xa[j])[e];
                    Bs[nxt][sc + 4 * j + e][sr] = ((const float*)&wb[j])[e];
                }
            __syncthreads();
            cur = nxt;
        }
    }

    // epilogue: scatter via probed relabel (layout-proof)
#pragma unroll
    for (int nt = 0; nt < 4; ++nt) {
#pragma unroll
        for (int mt = 0; mt < 4; ++mt) {
#pragma unroll
            for (int v = 0; v < 4; ++v) {
                const int row = m0 + wr + mt * 16 + ri[v];
                const int col = n0 + wc + nt * 16 + cj[v];
                const double val = acc[mt][nt][v] + (double)bias[col];
                if (MODE == 0) Yd[(size_t)row * D_ + col] = val;
                else           Yf[(size_t)row * D_ + col] = (float)val;
            }
        }
    }
}

#else  // !HAVE_MFMA_F64 — round-2 proven VALU fallback
constexpr int BM = 128, BN = 128, BK = 16;

template <int MODE>
__global__ __launch_bounds__(256, 2) void gemm_k(
    const float* __restrict__ X, const float* __restrict__ W,
    const float* __restrict__ bias, double* __restrict__ Yd,
    float* __restrict__ Yf)
{
    __shared__ float As[BK][BM + 4];
    __shared__ float Bs[BK][BN + 4];
    const int wid = blockIdx.x;
    const int swz = (wid & 7) * 64 + (wid >> 3);
    const int bx  = swz >> 5;
    const int by  = swz & 31;
    const int m0 = by * BM, n0 = bx * BN;
    const int tid = threadIdx.x;
    const int lr = tid >> 2;
    const int lc = (tid & 3) << 2;
    const float* xg = X + (size_t)(m0 + lr) * D_ + lc;
    const float* wg = W + (size_t)(n0 + lr) * D_ + lc;
    const int tx = tid & 15;
    const int ty = tid >> 4;

    double acc[8][8];
#pragma unroll
    for (int i = 0; i < 8; ++i)
#pragma unroll
        for (int j = 0; j < 8; ++j) acc[i][j] = 0.0;

    for (int k0 = 0; k0 < D_; k0 += BK) {
        float4 a0 = *(const float4*)(xg + k0);
        float4 a1 = *(const float4*)(xg + (size_t)64 * D_ + k0);
        float4 b0 = *(const float4*)(wg + k0);
        float4 b1 = *(const float4*)(wg + (size_t)64 * D_ + k0);
        __syncthreads();
        As[lc + 0][lr] = a0.x; As[lc + 1][lr] = a0.y;
        As[lc + 2][lr] = a0.z; As[lc + 3][lr] = a0.w;
        As[lc + 0][64 + lr] = a1.x; As[lc + 1][64 + lr] = a1.y;
        As[lc + 2][64 + lr] = a1.z; As[lc + 3][64 + lr] = a1.w;
        Bs[lc + 0][lr] = b0.x; Bs[lc + 1][lr] = b0.y;
        Bs[lc + 2][lr] = b0.z; Bs[lc + 3][lr] = b0.w;
        Bs[lc + 0][64 + lr] = b1.x; Bs[lc + 1][64 + lr] = b1.y;
        Bs[lc + 2][64 + lr] = b1.z; Bs[lc + 3][64 + lr] = b1.w;
        __syncthreads();
#pragma unroll
        for (int k = 0; k < BK; ++k) {
            float af[8], bf[8];
            *(float4*)&af[0] = *(const float4*)&As[k][ty * 4];
            *(float4*)&af[4] = *(const float4*)&As[k][64 + ty * 4];
            *(float4*)&bf[0] = *(const float4*)&Bs[k][tx * 4];
            *(float4*)&bf[4] = *(const float4*)&Bs[k][64 + tx * 4];
            double ad[8], bd[8];
#pragma unroll
            for (int i = 0; i < 8; ++i) { ad[i] = (double)af[i]; bd[i] = (double)bf[i]; }
#pragma unroll
            for (int i = 0; i < 8; ++i)
#pragma unroll
                for (int j = 0; j < 8; ++j)
                    acc[i][j] = fma(ad[i], bd[j], acc[i][j]);
        }
    }
#pragma unroll
    for (int jh = 0; jh < 2; ++jh) {
        const int col = n0 + jh * 64 + tx * 4;
        const float4 bb4 = *(const float4*)&bias[col];
        const double bb[4] = {(double)bb4.x, (double)bb4.y,
                              (double)bb4.z, (double)bb4.w};
#pragma unroll
        for (int ih = 0; ih < 2; ++ih)
#pragma unroll
            for (int i = 0; i < 4; ++i) {
                const int r = m0 + ih * 64 + ty * 4 + i;
#pragma unroll
                for (int v = 0; v < 4; ++v) {
                    const double val = acc[ih * 4 + i][jh * 4 + v] + bb[v];
                    if (MODE == 0) Yd[(size_t)r * D_ + col + v] = val;
                    else           Yf[(size_t)r * D_ + col + v] = (float)val;
                }
            }
    }
}
#endif  // HAVE_MFMA_F64

// ---------------------------------------------------------------------------
// Per-row LayerNorm stats in f64: stats[row] = {mean, rstd}
// ---------------------------------------------------------------------------
template <bool SRC64>
__global__ __launch_bounds__(256) void ln_stats_k(
    const void* __restrict__ Ysrc, double* __restrict__ stats)
{
    __shared__ double red[8];
    const int row = blockIdx.x;
    const int tid = threadIdx.x;
    double a[8];
    if constexpr (SRC64) {
        const double2* y = (const double2*)((const double*)Ysrc + (size_t)row * D_);
        double2 u0 = y[tid], u1 = y[tid + 256], u2 = y[tid + 512], u3 = y[tid + 768];
        a[0] = u0.x; a[1] = u0.y; a[2] = u1.x; a[3] = u1.y;
        a[4] = u2.x; a[5] = u2.y; a[6] = u3.x; a[7] = u3.y;
    } else {
        const float4* y = (const float4*)((const float*)Ysrc + (size_t)row * D_);
        float4 u0 = y[tid], u1 = y[tid + 256];
        a[0] = u0.x; a[1] = u0.y; a[2] = u0.z; a[3] = u0.w;
        a[4] = u1.x; a[5] = u1.y; a[6] = u1.z; a[7] = u1.w;
    }

    double s = 0.0;
#pragma unroll
    for (int i = 0; i < 8; ++i) s += a[i];
#pragma unroll
    for (int off = 32; off > 0; off >>= 1) s += __shfl_xor(s, off);
    const int lane = tid & 63, wv = tid >> 6;
    if (lane == 0) red[wv] = s;
    __syncthreads();
    const double mean = (red[0] + red[1] + red[2] + red[3]) * (1.0 / D_);

    double d2 = 0.0;
#pragma unroll
    for (int i = 0; i < 8; ++i) { double d = a[i] - mean; d2 += d * d; }
#pragma unroll
    for (int off = 32; off > 0; off >>= 1) d2 += __shfl_xor(d2, off);
    if (lane == 0) red[4 + wv] = d2;
    __syncthreads();
    if (tid == 0) {
        const double var = (red[4] + red[5] + red[6] + red[7]) * (1.0 / D_);
        stats[2 * row]     = mean;
        stats[2 * row + 1] = 1.0 / sqrt(var + LN_EPS);
    }
}

// ---------------------------------------------------------------------------
// LN-affine + residual + 32-step LIF in f64; spikes (f32) to d_out.
// ---------------------------------------------------------------------------
template <bool SRC64>
__global__ __launch_bounds__(256) void lif_k(
    const float* __restrict__ X, const float* __restrict__ lnw,
    const float* __restrict__ lnb, const double* __restrict__ stats,
    const void* __restrict__ Ysrc, float* __restrict__ out)
{
    const int q  = blockIdx.x * blockDim.x + threadIdx.x;  // 0..65535
    const int e4 = q & (D_ / 4 - 1);
    const int bi = q >> 9;

    const float4 w4 = ((const float4*)lnw)[e4];
    const float4 b4 = ((const float4*)lnb)[e4];
    const double w[4]  = {(double)w4.x, (double)w4.y, (double)w4.z, (double)w4.w};
    const double bb[4] = {(double)b4.x, (double)b4.y, (double)b4.z, (double)b4.w};
    double v[4] = {0.0, 0.0, 0.0, 0.0};

    for (int t = 0; t < T_; ++t) {
        const int row = t * B_ + bi;
        const double mu = stats[2 * row];
        const double rs = stats[2 * row + 1];
        double y[4];
        if constexpr (SRC64) {
            const double2* yp = (const double2*)((const double*)Ysrc +
                                                 (size_t)row * D_ + e4 * 4);
            double2 u0 = yp[0], u1 = yp[1];
            y[0] = u0.x; y[1] = u0.y; y[2] = u1.x; y[3] = u1.y;
        } else {
            float4 y4 = ((const float4*)Ysrc)[(size_t)row * (D_ / 4) + e4];
            y[0] = y4.x; y[1] = y4.y; y[2] = y4.z; y[3] = y4.w;
        }
        const float4 x4 = ((const float4*)X)[(size_t)row * (D_ / 4) + e4];
        const double xr[4] = {(double)x4.x, (double)x4.y, (double)x4.z, (double)x4.w};
        float sp[4];
#pragma unroll
        for (int c = 0; c < 4; ++c) {
            const double z   = (y[c] - mu) * rs * w[c] + bb[c];
            const double xin = z + xr[c];
            const double h   = v[c] + (xin - v[c]) * 0.5;
            const bool fire  = (h - 1.0) >= 0.0;
            sp[c] = fire ? 1.0f : 0.0f;
            v[c]  = fire ? 0.0 : h;
        }
        float4 o = {sp[0], sp[1], sp[2], sp[3]};
        ((float4*)out)[(size_t)row * (D_ / 4) + e4] = o;
    }
}

// ---------------------------------------------------------------------------
extern "C" void kernel_launch(void* const* d_in, const int* in_sizes, int n_in,
                              void* d_out, int out_size, void* d_ws, size_t ws_size,
                              hipStream_t stream)
{
    const float* X    = (const float*)d_in[0];
    const float* W    = (const float*)d_in[1];
    const float* bias = (const float*)d_in[2];
    const float* lnw  = (const float*)d_in[3];
    const float* lnb  = (const float*)d_in[4];
    float* out = (float*)d_out;

    const bool big = ws_size >= YD_BYTES + ST_BYTES;   // deterministic branch

    if (big) {
        double* Yd    = (double*)d_ws;
        double* stats = (double*)((char*)d_ws + YD_BYTES);
        gemm_k<0><<<dim3(512), dim3(256), 0, stream>>>(X, W, bias, Yd, nullptr);
        ln_stats_k<true><<<dim3(M_), dim3(256), 0, stream>>>(Yd, stats);
        lif_k<true><<<dim3((B_ * D_ / 4) / 256), dim3(256), 0, stream>>>(
            X, lnw, lnb, stats, Yd, out);
    } else {
        double* stats = (double*)d_ws;                 // needs 64 KiB
        gemm_k<1><<<dim3(512), dim3(256), 0, stream>>>(X, W, bias, nullptr, out);
        ln_stats_k<false><<<dim3(M_), dim3(256), 0, stream>>>(out, stats);
        lif_k<false><<<dim3((B_ * D_ / 4) / 256), dim3(256), 0, stream>>>(
            X, lnw, lnb, stats, out, out);
    }
}